// Round 2
// 349.124 us; speedup vs baseline: 1.0533x; 1.0533x over previous
//
#include <hip/hip_runtime.h>

// RandomEqualize: PIL-style histogram equalization per (batch, channel).
// Input: float32 (64,3,512,512), exact integer values in [0,255].
// N = 192 channels, P = 262144 pixels/channel.
//
// 2-kernel pipeline:
//  K1: per-block LDS histogram (32 bank-strided copies, ds_add) -> partials,
//      AND packs clamped pixels to u8 in ws (cached stores -> L3-resident).
//  K2: per-block: reduce 4 partials -> PIL LUT (scan in LDS) -> 32x
//      bank-replicated LUT gather applied to the u8 stream; NT float4 stores.
//      (LUT build is 4x-redundant per channel but <1us and overlaps mem work.)

#define NBINS 256
#define BPC 4                   // blocks per channel
#define CHUNK 65536             // P / BPC pixels per block
#define NVEC (CHUNK / 4)        // 4-pixel packets per block = 16384

typedef float vfloat4 __attribute__((ext_vector_type(4)));

// ---------------- K1: histogram + u8 pack ----------------
__global__ __launch_bounds__(256) void eq_hist_pack_kernel(
    const float* __restrict__ in, unsigned int* __restrict__ pack,
    unsigned int* __restrict__ phist) {
    __shared__ unsigned int lh[NBINS * 32];  // 32 KB, word (bin*32+copy) -> bank=copy
    const int t = threadIdx.x;
    const int copy = t & 31;
    const int chan = blockIdx.x >> 2;   // BPC = 4
    const int blk  = blockIdx.x & 3;

    for (int i = t; i < NBINS * 32; i += 256) lh[i] = 0u;
    __syncthreads();

    const size_t basev = ((size_t)chan * (size_t)(CHUNK * BPC) +
                          (size_t)blk * CHUNK) >> 2;   // in float4 / u32 units
    const float4* vin = (const float4*)in + basev;
    unsigned int* pout = pack + basev;   // one packed u32 per 4 pixels

    #pragma unroll 4
    for (int i = t; i < NVEC; i += 256) {
        float4 v = vin[i];
        int ix = min(max((int)v.x, 0), 255);
        int iy = min(max((int)v.y, 0), 255);
        int iz = min(max((int)v.z, 0), 255);
        int iw = min(max((int)v.w, 0), 255);
        atomicAdd(&lh[ix * 32 + copy], 1u);
        atomicAdd(&lh[iy * 32 + copy], 1u);
        atomicAdd(&lh[iz * 32 + copy], 1u);
        atomicAdd(&lh[iw * 32 + copy], 1u);
        pout[i] = (unsigned)ix | ((unsigned)iy << 8) |
                  ((unsigned)iz << 16) | ((unsigned)iw << 24);
    }
    __syncthreads();

    // thread t owns bin t; staggered copy index keeps lanes on distinct banks
    unsigned int s = 0;
    #pragma unroll
    for (int c = 0; c < 32; ++c) s += lh[t * 32 + ((t + c) & 31)];
    phist[(size_t)blockIdx.x * NBINS + t] = s;   // partial, no atomics
}

// ---------------- K2: LUT build + apply ----------------
__global__ __launch_bounds__(256) void eq_lut_apply_kernel(
    const unsigned int* __restrict__ pack, const unsigned int* __restrict__ phist,
    float* __restrict__ out, int P) {
    __shared__ float slut[NBINS * 32];   // 32 KB, bank-replicated LUT
    __shared__ unsigned int s[NBINS];
    __shared__ int sidx[NBINS];
    const int t = threadIdx.x;
    const int copy = t & 31;
    const int chan = blockIdx.x >> 2;
    const int blk  = blockIdx.x & 3;

    // per-channel hist from BPC partials
    unsigned int h = 0;
    const unsigned int* pb = phist + (size_t)chan * BPC * NBINS;
    #pragma unroll
    for (int b = 0; b < BPC; ++b) h += pb[b * NBINS + t];
    s[t] = h;
    sidx[t] = (h != 0u) ? t : -1;
    __syncthreads();

    // max-reduce: last nonzero bin index
    for (int off = 128; off > 0; off >>= 1) {
        if (t < off) sidx[t] = max(sidx[t], sidx[t + off]);
        __syncthreads();
    }
    const int last_idx = sidx[0];
    const int last_val = (int)s[last_idx];
    const int step = (P - last_val) / 255;

    // Hillis-Steele inclusive scan
    for (int off = 1; off < NBINS; off <<= 1) {
        unsigned int v = (t >= off) ? s[t - off] : 0u;
        __syncthreads();
        s[t] += v;
        __syncthreads();
    }

    float lv;
    if (step == 0) {
        lv = (float)t;   // pass-through: identity LUT
    } else {
        int csp = (t == 0) ? 0 : (int)s[t - 1];
        int l = (csp + (step >> 1)) / step;
        lv = (float)min(max(l, 0), 255);
    }
    #pragma unroll
    for (int c = 0; c < 32; ++c)
        slut[t * 32 + ((t + c) & 31)] = lv;   // bank (t+c)&31: 2-way, free
    __syncthreads();

    const size_t basev = ((size_t)chan * (size_t)(CHUNK * BPC) +
                          (size_t)blk * CHUNK) >> 2;
    const unsigned int* pin = pack + basev;     // u8 pixels, L3-resident
    vfloat4* vout = (vfloat4*)out + basev;

    #pragma unroll 4
    for (int i = t; i < NVEC; i += 256) {
        unsigned int p = pin[i];
        vfloat4 r;
        r.x = slut[(p & 255u) * 32 + copy];
        r.y = slut[((p >> 8) & 255u) * 32 + copy];
        r.z = slut[((p >> 16) & 255u) * 32 + copy];
        r.w = slut[(p >> 24) * 32 + copy];
        __builtin_nontemporal_store(r, &vout[i]);
    }
}

extern "C" void kernel_launch(void* const* d_in, const int* in_sizes, int n_in,
                              void* d_out, int out_size, void* d_ws, size_t ws_size,
                              hipStream_t stream) {
    const float* img = (const float*)d_in[0];
    float* out = (float*)d_out;

    const int P = 512 * 512;        // pixels per channel
    const int total = in_sizes[0];  // 64*3*512*512 elements
    const int N = total / P;        // 192 channels

    // ws layout: packed u8 pixels (total bytes) | partial hists
    unsigned int* pack  = (unsigned int*)d_ws;
    unsigned int* phist = (unsigned int*)((char*)d_ws + (size_t)total);

    eq_hist_pack_kernel<<<N * BPC, 256, 0, stream>>>(img, pack, phist);
    eq_lut_apply_kernel<<<N * BPC, 256, 0, stream>>>(pack, phist, out, P);
}